// Round 13
// baseline (1825.487 us; speedup 1.0000x reference)
//
#include <hip/hip_runtime.h>
#include <cmath>

// DHT: out[n,c,a,r] = sum over px (x,y) of feat[n,c,y,x],
//   r = rint((x-128)*cos(a deg) + (y-128)*sin(a deg)) + 361  (r in [180,542])
// feat[4,128,256,256] f32 -> out[4,128,180,723] f32.
//
// Locked-in findings:
//  R1-R4 (~31ms): LDS f32 atomicAdd serializes ~per-lane -> never on hot path.
//  R5 (2.69ms): wave-private rows + plain program-ordered DS RMW, race-free
//    when concurrent lanes' bins provably distinct.
//  R6 (3.88ms): image re-reads at >1 block/CU -> HBM-bound. R10: exec-masked
//    DS RMW poison. R11: occupancy not binding. R9/R11: b64 swizzle
//    numerology failed 3x.
//  R7 (1.85ms): register-persistent px across ALL angles (FETCH 0.6GB).
//  R8 (1.66ms) / R12 (1.54ms): b64 pair-RMW; R12 dropped swizzle (VALU win),
//    but conflicts INVARIANT (~2.8e8) at b64 regardless of stride 2.83-8.
//  R13: split the pair into TWO b32 RMW streams (img0/img1 rows in separate
//    LDS regions, same index, one vaddr + offset: immediate). b32 lane
//    word-stride 2|coef| in [1.41,2] = m136's measured 2-way-FREE regime.
//    Port bytes invariant; DS issue 2x. DISCRIMINATOR: conflicts vanish ->
//    conflict-bound confirmed (~1.3ms); time rises -> issue-bound, go b128.

#define NA 180
#define NR 723
#define HW 65536
#define NC 512
#define CH 2            // angles per LDS chunk
#define ROW_W 368       // bins rl = r-RBASE in [4,366]
#define ROW_PAD 368
#define RBASE 176
#define NWIN 32         // 8-px windows along the scan axis
#define OFF (16 * CH * ROW_PAD)   // img1 region element offset (47104 B)

__device__ __forceinline__ bool is_phase2(int a) { return a >= 46 && a <= 134; }

// ---------------------------------------------------------------------------
// win[a][w][fast] u32 = base bin at scan=8w (bits 0..15), step bits 16..22.
// Phase-1 (a in [0,45]u[135,179]): fast=x, scan=y (step coef sin(a)>=0).
// Phase-2 (a in [46,134]):         fast=y, scan=x (step coef cos(a), sign
// flips at a=90). fp64 non-fused mul/add + rint bit-matches np.round
// (validated R1-R12: absmax 0.25 = f32 sum-order noise only).
// ---------------------------------------------------------------------------
__global__ __launch_bounds__(256) void dht_win(unsigned int* __restrict__ win) {
    const int lane = threadIdx.x;
    const int w = blockIdx.x;
    const int a = blockIdx.y;
    const double theta = (double)a * (M_PI / 180.0);
    const double c = cos(theta), s = sin(theta);
    const bool p2 = is_phase2(a);
    int prev = 0;
    unsigned int word = 0;
    #pragma unroll
    for (int i = 0; i < 8; ++i) {
        const int k = w * 8 + i;
        const int x = p2 ? k : lane;
        const int y = p2 ? lane : k;
        const double rho = __dadd_rn(__dmul_rn((double)(x - 128), c),
                                     __dmul_rn((double)(y - 128), s));
        int r = (int)rint(rho) + 361;
        r = min(max(r, 0), NR - 1);
        if (i == 0) word = (unsigned int)r;
        else if (r != prev) word |= (1u << (15 + i));
        prev = r;
    }
    win[((size_t)a * NWIN + w) * 256 + lane] = word;
}

__global__ __launch_bounds__(256) void zero_out(float4* __restrict__ o, int n4) {
    const int i = blockIdx.x * 256 + threadIdx.x;
    if (i < n4) o[i] = make_float4(0.f, 0.f, 0.f, 0.f);
}

// Branchless 8(scan) x 4(col) x 2(img) walk; TWO b32 RMW streams sharing one
// element index (img1 region at compile-time offset -> DS offset: immediate).
// Concurrent lanes (fixed j) sit 2 columns apart -> bin spacing >= 1.414 ->
// distinct addresses in both streams -> race-free.
template <int SGN>
__device__ __forceinline__ void walk2(const uint4 wq, const float2 (&px)[8][4],
                                      float* __restrict__ rp0) {
    #pragma unroll
    for (int j = 0; j < 4; ++j) {
        const unsigned int wrd = (&wq.x)[j];
        int bin = (int)(wrd & 0xffffu) - RBASE;
        #pragma unroll
        for (int k = 0; k < 8; ++k) {
            if (k) bin += SGN * (int)((wrd >> (15 + k)) & 1u);
            const float v0 = rp0[bin];
            const float v1 = rp0[bin + OFF];
            rp0[bin]       = v0 + px[k][j].x;
            rp0[bin + OFF] = v1 + px[k][j].y;
        }
    }
}

// ---------------------------------------------------------------------------
// Block = (image-pair, phase, scan-half). 1024 thr = 16 waves; wave wv owns
// scan window w = 16h+wv (8 scan lines); lane owns fast columns
// {2l, 2l+1, 2l+128, 2l+129} (j = 0..3). px float2[8][4] loaded ONCE,
// reused across all angles of the phase. rows = 2 x 47.1 KB -> 1 block/CU.
// ---------------------------------------------------------------------------
__global__ __launch_bounds__(1024, 4) void dht_main(const float* __restrict__ feat,
                                                    const unsigned int* __restrict__ win,
                                                    float* __restrict__ out) {
    __shared__ float rows[2 * OFF];   // 94.2 KB: img0 at [0], img1 at [OFF]
    const int t = threadIdx.x;
    const int wv = t >> 6;
    const int l = t & 63;
    const int pair = blockIdx.x;
    const int phase = blockIdx.y;
    const int h = blockIdx.z;
    const int w = 16 * h + wv;          // scan window 0..31
    const int k0 = 8 * w;               // scan offset
    const float* __restrict__ f0 = feat + (size_t)(2 * pair) * HW;
    const float* __restrict__ f1 = feat + (size_t)(2 * pair + 1) * HW;
    float* __restrict__ o0 = out + (size_t)(2 * pair) * (NA * NR);
    float* __restrict__ o1 = out + (size_t)(2 * pair + 1) * (NA * NR);

    // fast-axis indices owned by this lane (j = 0..3)
    const int fj0 = 2 * l;        // and fj0+1
    const int fj2 = 2 * l + 128;  // and fj2+1

    // ---- load persistent px tile: 8 scan x 4 fast x 2 img ----
    float2 px[8][4];
    if (phase == 0) {
        // scan=y: row y=k0+k; fast=x at {2l,2l+1} and {2l+128,2l+129}
        #pragma unroll
        for (int k = 0; k < 8; ++k) {
            const float2 a0 = *(const float2*)(f0 + ((k0 + k) << 8) + fj0);
            const float2 a1 = *(const float2*)(f0 + ((k0 + k) << 8) + fj2);
            const float2 b0 = *(const float2*)(f1 + ((k0 + k) << 8) + fj0);
            const float2 b1 = *(const float2*)(f1 + ((k0 + k) << 8) + fj2);
            px[k][0] = make_float2(a0.x, b0.x); px[k][1] = make_float2(a0.y, b0.y);
            px[k][2] = make_float2(a1.x, b1.x); px[k][3] = make_float2(a1.y, b1.y);
        }
    } else {
        // scan=x: fast=y rows {2l,2l+1,2l+128,2l+129}; cols x=k0..k0+7
        #pragma unroll
        for (int j = 0; j < 4; ++j) {
            const int fr = (j < 2) ? (fj0 + j) : (fj2 + (j - 2));
            const float4 q0 = *(const float4*)(f0 + (fr << 8) + k0);
            const float4 q1 = *(const float4*)(f0 + (fr << 8) + k0 + 4);
            const float4 r0 = *(const float4*)(f1 + (fr << 8) + k0);
            const float4 r1 = *(const float4*)(f1 + (fr << 8) + k0 + 4);
            px[0][j] = make_float2(q0.x, r0.x); px[1][j] = make_float2(q0.y, r0.y);
            px[2][j] = make_float2(q0.z, r0.z); px[3][j] = make_float2(q0.w, r0.w);
            px[4][j] = make_float2(q1.x, r1.x); px[5][j] = make_float2(q1.y, r1.y);
            px[6][j] = make_float2(q1.z, r1.z); px[7][j] = make_float2(q1.w, r1.w);
        }
    }

    const int nAng = phase ? 89 : 91;
    for (int cb = 0; cb < nAng; cb += CH) {
        const int cn = min(CH, nAng - cb);
        for (int i = t; i < 2 * OFF; i += 1024) rows[i] = 0.f;
        __syncthreads();

        for (int ai = 0; ai < cn; ++ai) {
            const int aidx = cb + ai;
            const int a = phase ? (46 + aidx) : (aidx <= 45 ? aidx : aidx + 89);
            const unsigned int* wrow = win + ((size_t)a * NWIN + w) * 256;
            const uint2 u0 = *(const uint2*)(wrow + fj0);   // cols 2l, 2l+1
            const uint2 u1 = *(const uint2*)(wrow + fj2);   // cols 2l+128, 2l+129
            uint4 wq; wq.x = u0.x; wq.y = u0.y; wq.z = u1.x; wq.w = u1.y;
            float* __restrict__ rp0 = rows + (wv * CH + ai) * ROW_PAD;
            if (phase && a > 90) walk2<-1>(wq, px, rp0);
            else                 walk2<+1>(wq, px, rp0);
        }
        __syncthreads();

        // flush: lanes iterate rl contiguously -> stride-1 LDS reads (free)
        // and contiguous global atomics. Exactly-2 atomic contributions per
        // out element (two scan-halves) -> deterministic.
        for (int i = t; i < cn * ROW_W; i += 1024) {
            const int al = i / ROW_W;
            const int rl = i - al * ROW_W;
            const int ad = (al /*wave-copy sum*/, rl);
            float sx = 0.f, sy = 0.f;
            #pragma unroll
            for (int c2 = 0; c2 < 16; ++c2) {
                const int base = (c2 * CH + al) * ROW_PAD + rl;
                sx += rows[base];
                sy += rows[base + OFF];
            }
            const int aidx = cb + al;
            const int a = phase ? (46 + aidx) : (aidx <= 45 ? aidx : aidx + 89);
            const size_t o = (size_t)a * NR + (RBASE + rl);
            unsafeAtomicAdd(o0 + o, sx);
            unsafeAtomicAdd(o1 + o, sy);
        }
        __syncthreads();
    }
}

extern "C" void kernel_launch(void* const* d_in, const int* in_sizes, int n_in,
                              void* d_out, int out_size, void* d_ws, size_t ws_size,
                              hipStream_t stream) {
    const float* feat = (const float*)d_in[0];
    float* out = (float*)d_out;
    unsigned int* win = (unsigned int*)d_ws;

    const size_t win_bytes = (size_t)NA * NWIN * 256 * sizeof(unsigned int); // 5.9MB
    if (ws_size < win_bytes) return;

    const int n4 = out_size / 4;   // out_size = 512*180*723, divisible by 4
    hipLaunchKernelGGL(zero_out, dim3((n4 + 255) / 256), dim3(256), 0, stream,
                       (float4*)out, n4);
    hipLaunchKernelGGL(dht_win, dim3(NWIN, NA), dim3(256), 0, stream, win);
    hipLaunchKernelGGL(dht_main, dim3(NC / 2, 2, 2), dim3(1024), 0, stream,
                       feat, win, out);
}

// Round 14
// 1508.509 us; speedup vs baseline: 1.2101x; 1.2101x over previous
//
#include <hip/hip_runtime.h>
#include <cmath>

// DHT: out[n,c,a,r] = sum over px (x,y) of feat[n,c,y,x],
//   r = rint((x-128)*cos(a deg) + (y-128)*sin(a deg)) + 361  (r in [180,542])
// feat[4,128,256,256] f32 -> out[4,128,180,723] f32.
//
// Locked-in findings:
//  R1-R4 (~31ms): LDS f32 atomicAdd serializes ~per-lane -> never on hot path.
//  R5 (2.69ms): wave-private rows + plain program-ordered DS RMW, race-free
//    when concurrent lanes' bins provably distinct.
//  R6: image re-reads at >1 block/CU -> HBM-bound. R10: exec-masked DS RMW
//    poison. R11: occupancy not binding.
//  R7 (1.85ms): register-persistent px across ALL angles.
//  R12 (1.54ms, BEST): b64 pair-RMW, stride-2 lane columns, no swizzle.
//  R8/R9/R11/R13: lane-address swizzles NEVER moved the ~2.8e8 conflict
//    count (R13's b32 split was confounded: region offset was 0 mod 32).
//  THEORY: conflicts are bank collisions between CONSECUTIVE DS ops in the
//    RMW stream (write_k vs read_{k+1}: bins differ 0/±1 -> same bank).
//  R14: interleave the TWO angles of each chunk in one walk (a0-RMW, a1-RMW
//    alternating). Angle rows padded to ROW_PAD=372 -> row stride 744 words
//    == 8 mod 32 -> consecutive DS ops ~8 banks apart. Discriminator:
//    conflicts drop -> adjacency theory; invariant -> intrinsic RMW tax.

#define NA 180
#define NR 723
#define HW 65536
#define NC 512
#define CH 2            // angles per LDS chunk
#define ROW_W 368       // bins rl = r-RBASE in [4,366]
#define ROW_PAD 372     // float2 elems; row stride 744 words == 8 mod 32
#define RBASE 176
#define NWIN 32         // 8-px windows along the scan axis

__device__ __forceinline__ bool is_phase2(int a) { return a >= 46 && a <= 134; }

// ---------------------------------------------------------------------------
// win[a][w][fast] u32 = base bin at scan=8w (bits 0..15), step bits 16..22.
// Phase-1 (a in [0,45]u[135,179]): fast=x, scan=y (step coef sin(a)>=0).
// Phase-2 (a in [46,134]):         fast=y, scan=x (step coef cos(a), sign
// flips at a=90). fp64 non-fused mul/add + rint bit-matches np.round
// (validated R1-R13: absmax 0.25 = f32 sum-order noise only).
// ---------------------------------------------------------------------------
__global__ __launch_bounds__(256) void dht_win(unsigned int* __restrict__ win) {
    const int lane = threadIdx.x;
    const int w = blockIdx.x;
    const int a = blockIdx.y;
    const double theta = (double)a * (M_PI / 180.0);
    const double c = cos(theta), s = sin(theta);
    const bool p2 = is_phase2(a);
    int prev = 0;
    unsigned int word = 0;
    #pragma unroll
    for (int i = 0; i < 8; ++i) {
        const int k = w * 8 + i;
        const int x = p2 ? k : lane;
        const int y = p2 ? lane : k;
        const double rho = __dadd_rn(__dmul_rn((double)(x - 128), c),
                                     __dmul_rn((double)(y - 128), s));
        int r = (int)rint(rho) + 361;
        r = min(max(r, 0), NR - 1);
        if (i == 0) word = (unsigned int)r;
        else if (r != prev) word |= (1u << (15 + i));
        prev = r;
    }
    win[((size_t)a * NWIN + w) * 256 + lane] = word;
}

__global__ __launch_bounds__(256) void zero_out(float4* __restrict__ o, int n4) {
    const int i = blockIdx.x * 256 + threadIdx.x;
    if (i < n4) o[i] = make_float4(0.f, 0.f, 0.f, 0.f);
}

// Single-angle walk (R12 form) for odd tail chunks.
template <int SGN>
__device__ __forceinline__ void walk2(const uint4 wq, const float2 (&px)[8][4],
                                      float2* __restrict__ rp) {
    #pragma unroll
    for (int j = 0; j < 4; ++j) {
        const unsigned int wrd = (&wq.x)[j];
        int bin = (int)(wrd & 0xffffu) - RBASE;
        #pragma unroll
        for (int k = 0; k < 8; ++k) {
            if (k) bin += SGN * (int)((wrd >> (15 + k)) & 1u);
            float2 v = rp[bin];
            v.x += px[k][j].x; v.y += px[k][j].y;
            rp[bin] = v;
        }
    }
}

// Dual-angle interleaved walk: alternating a0/a1 RMWs so consecutive DS ops
// target rows 744 words (== 8 banks) apart. Per-angle semantics identical to
// walk2 (same k,j order -> same f32 sum order as R12). Race-free: distinct
// rows per angle; within an angle, lane bins >= 1.414 apart (stride-2 cols).
template <int SGN0, int SGN1>
__device__ __forceinline__ void walk2x2(const uint4 wq0, const uint4 wq1,
                                        const float2 (&px)[8][4],
                                        float2* __restrict__ rp0,
                                        float2* __restrict__ rp1) {
    #pragma unroll
    for (int j = 0; j < 4; ++j) {
        const unsigned int wrd0 = (&wq0.x)[j];
        const unsigned int wrd1 = (&wq1.x)[j];
        int b0 = (int)(wrd0 & 0xffffu) - RBASE;
        int b1 = (int)(wrd1 & 0xffffu) - RBASE;
        #pragma unroll
        for (int k = 0; k < 8; ++k) {
            if (k) {
                b0 += SGN0 * (int)((wrd0 >> (15 + k)) & 1u);
                b1 += SGN1 * (int)((wrd1 >> (15 + k)) & 1u);
            }
            float2 v0 = rp0[b0];
            v0.x += px[k][j].x; v0.y += px[k][j].y;
            rp0[b0] = v0;
            float2 v1 = rp1[b1];
            v1.x += px[k][j].x; v1.y += px[k][j].y;
            rp1[b1] = v1;
        }
    }
}

// ---------------------------------------------------------------------------
// Block = (image-pair, phase, scan-half). 1024 thr = 16 waves; wave wv owns
// scan window w = 16h+wv (8 scan lines); lane owns fast columns
// {2l, 2l+1, 2l+128, 2l+129} (j = 0..3). px float2[8][4] loaded ONCE,
// reused across all angles of the phase.
// rows[16 waves][CH][ROW_PAD] float2 = 93 KB -> 1 block/CU.
// ---------------------------------------------------------------------------
__global__ __launch_bounds__(1024, 4) void dht_main(const float* __restrict__ feat,
                                                    const unsigned int* __restrict__ win,
                                                    float* __restrict__ out) {
    __shared__ float2 rows[16 * CH * ROW_PAD];   // 93 KB
    const int t = threadIdx.x;
    const int wv = t >> 6;
    const int l = t & 63;
    const int pair = blockIdx.x;
    const int phase = blockIdx.y;
    const int h = blockIdx.z;
    const int w = 16 * h + wv;          // scan window 0..31
    const int k0 = 8 * w;               // scan offset
    const float* __restrict__ f0 = feat + (size_t)(2 * pair) * HW;
    const float* __restrict__ f1 = feat + (size_t)(2 * pair + 1) * HW;
    float* __restrict__ o0 = out + (size_t)(2 * pair) * (NA * NR);
    float* __restrict__ o1 = out + (size_t)(2 * pair + 1) * (NA * NR);

    // fast-axis indices owned by this lane (j = 0..3)
    const int fj0 = 2 * l;        // and fj0+1
    const int fj2 = 2 * l + 128;  // and fj2+1

    // ---- load persistent px tile: 8 scan x 4 fast x 2 img ----
    float2 px[8][4];
    if (phase == 0) {
        // scan=y: row y=k0+k; fast=x at {2l,2l+1} and {2l+128,2l+129}
        #pragma unroll
        for (int k = 0; k < 8; ++k) {
            const float2 a0 = *(const float2*)(f0 + ((k0 + k) << 8) + fj0);
            const float2 a1 = *(const float2*)(f0 + ((k0 + k) << 8) + fj2);
            const float2 b0 = *(const float2*)(f1 + ((k0 + k) << 8) + fj0);
            const float2 b1 = *(const float2*)(f1 + ((k0 + k) << 8) + fj2);
            px[k][0] = make_float2(a0.x, b0.x); px[k][1] = make_float2(a0.y, b0.y);
            px[k][2] = make_float2(a1.x, b1.x); px[k][3] = make_float2(a1.y, b1.y);
        }
    } else {
        // scan=x: fast=y rows {2l,2l+1,2l+128,2l+129}; cols x=k0..k0+7
        #pragma unroll
        for (int j = 0; j < 4; ++j) {
            const int fr = (j < 2) ? (fj0 + j) : (fj2 + (j - 2));
            const float4 q0 = *(const float4*)(f0 + (fr << 8) + k0);
            const float4 q1 = *(const float4*)(f0 + (fr << 8) + k0 + 4);
            const float4 r0 = *(const float4*)(f1 + (fr << 8) + k0);
            const float4 r1 = *(const float4*)(f1 + (fr << 8) + k0 + 4);
            px[0][j] = make_float2(q0.x, r0.x); px[1][j] = make_float2(q0.y, r0.y);
            px[2][j] = make_float2(q0.z, r0.z); px[3][j] = make_float2(q0.w, r0.w);
            px[4][j] = make_float2(q1.x, r1.x); px[5][j] = make_float2(q1.y, r1.y);
            px[6][j] = make_float2(q1.z, r1.z); px[7][j] = make_float2(q1.w, r1.w);
        }
    }

    const int nAng = phase ? 89 : 91;
    for (int cb = 0; cb < nAng; cb += CH) {
        const int cn = min(CH, nAng - cb);
        for (int i = t; i < 16 * CH * ROW_PAD; i += 1024)
            rows[i] = make_float2(0.f, 0.f);
        __syncthreads();

        const unsigned int* wbase = win;
        // angle ids of this chunk
        const int a0 = phase ? (46 + cb) : (cb <= 45 ? cb : cb + 89);
        if (cn == 2) {
            const int a1 = phase ? (a0 + 1) : ((cb + 1) <= 45 ? cb + 1 : cb + 90);
            const unsigned int* wr0 = wbase + ((size_t)a0 * NWIN + w) * 256;
            const unsigned int* wr1 = wbase + ((size_t)a1 * NWIN + w) * 256;
            const uint2 p00 = *(const uint2*)(wr0 + fj0);
            const uint2 p01 = *(const uint2*)(wr0 + fj2);
            const uint2 p10 = *(const uint2*)(wr1 + fj0);
            const uint2 p11 = *(const uint2*)(wr1 + fj2);
            uint4 wq0; wq0.x = p00.x; wq0.y = p00.y; wq0.z = p01.x; wq0.w = p01.y;
            uint4 wq1; wq1.x = p10.x; wq1.y = p10.y; wq1.z = p11.x; wq1.w = p11.y;
            float2* __restrict__ rp0 = rows + (wv * CH + 0) * ROW_PAD;
            float2* __restrict__ rp1 = rows + (wv * CH + 1) * ROW_PAD;
            if (phase == 0)        walk2x2<+1, +1>(wq0, wq1, px, rp0, rp1);
            else if (a1 <= 90)     walk2x2<+1, +1>(wq0, wq1, px, rp0, rp1);
            else if (a0 > 90)      walk2x2<-1, -1>(wq0, wq1, px, rp0, rp1);
            else                   walk2x2<+1, -1>(wq0, wq1, px, rp0, rp1);
        } else {
            const unsigned int* wr0 = wbase + ((size_t)a0 * NWIN + w) * 256;
            const uint2 p00 = *(const uint2*)(wr0 + fj0);
            const uint2 p01 = *(const uint2*)(wr0 + fj2);
            uint4 wq0; wq0.x = p00.x; wq0.y = p00.y; wq0.z = p01.x; wq0.w = p01.y;
            float2* __restrict__ rp0 = rows + (wv * CH + 0) * ROW_PAD;
            if (phase && a0 > 90) walk2<-1>(wq0, px, rp0);
            else                  walk2<+1>(wq0, px, rp0);
        }
        __syncthreads();

        // flush: lanes iterate rl contiguously -> contiguous global atomics.
        // Exactly-2 atomic contributions per out element -> deterministic.
        for (int i = t; i < cn * ROW_W; i += 1024) {
            const int al = i / ROW_W;
            const int rl = i - al * ROW_W;
            float sx = 0.f, sy = 0.f;
            #pragma unroll
            for (int c2 = 0; c2 < 16; ++c2) {
                const float2 v = rows[(c2 * CH + al) * ROW_PAD + rl];
                sx += v.x; sy += v.y;
            }
            const int aidx = cb + al;
            const int a = phase ? (46 + aidx) : (aidx <= 45 ? aidx : aidx + 89);
            const size_t o = (size_t)a * NR + (RBASE + rl);
            unsafeAtomicAdd(o0 + o, sx);
            unsafeAtomicAdd(o1 + o, sy);
        }
        __syncthreads();
    }
}

extern "C" void kernel_launch(void* const* d_in, const int* in_sizes, int n_in,
                              void* d_out, int out_size, void* d_ws, size_t ws_size,
                              hipStream_t stream) {
    const float* feat = (const float*)d_in[0];
    float* out = (float*)d_out;
    unsigned int* win = (unsigned int*)d_ws;

    const size_t win_bytes = (size_t)NA * NWIN * 256 * sizeof(unsigned int); // 5.9MB
    if (ws_size < win_bytes) return;

    const int n4 = out_size / 4;   // out_size = 512*180*723, divisible by 4
    hipLaunchKernelGGL(zero_out, dim3((n4 + 255) / 256), dim3(256), 0, stream,
                       (float4*)out, n4);
    hipLaunchKernelGGL(dht_win, dim3(NWIN, NA), dim3(256), 0, stream, win);
    hipLaunchKernelGGL(dht_main, dim3(NC / 2, 2, 2), dim3(1024), 0, stream,
                       feat, win, out);
}